// Round 2
// baseline (543.008 us; speedup 1.0000x reference)
//
#include <hip/hip_runtime.h>
#include <math.h>

// HashEncoder with spatial bin-sort for gather locality.
// Bins: 16x16x16 over [0,0.9)^3. Sorted records: float4{x,y,z,bitcast(idx)}.
// Pipeline: memset(hist) -> hist -> scan -> scatter -> encode.

#define BINS_X 16
#define NBINS  4096   // 16^3
#define BIN_SCALE (16.0f / 0.9f)

__device__ __forceinline__ int bin_of(float x, float y, float z) {
    int bx = (int)(x * BIN_SCALE); bx = bx < 0 ? 0 : (bx > 15 ? 15 : bx);
    int by = (int)(y * BIN_SCALE); by = by < 0 ? 0 : (by > 15 ? 15 : by);
    int bz = (int)(z * BIN_SCALE); bz = bz < 0 ? 0 : (bz > 15 ? 15 : bz);
    return bx | (by << 4) | (bz << 8);
}

__global__ __launch_bounds__(256) void hist_kernel(
    const float* __restrict__ pos, int n, int* __restrict__ hist)
{
    int i = blockIdx.x * blockDim.x + threadIdx.x;
    if (i >= n) return;
    float x = pos[3 * i + 0], y = pos[3 * i + 1], z = pos[3 * i + 2];
    atomicAdd(&hist[bin_of(x, y, z)], 1);
}

// Single block, 256 threads, 16 bins/thread: exclusive scan of hist -> cursor.
__global__ __launch_bounds__(256) void scan_kernel(
    const int* __restrict__ hist, int* __restrict__ cursor)
{
    __shared__ int partials[256];
    int t = threadIdx.x;
    int local[16];
    int sum = 0;
#pragma unroll
    for (int j = 0; j < 16; ++j) {
        local[j] = sum;               // exclusive within chunk
        sum += hist[t * 16 + j];
    }
    partials[t] = sum;
    __syncthreads();
    // Hillis-Steele inclusive scan over 256 partials
    for (int off = 1; off < 256; off <<= 1) {
        int v = (t >= off) ? partials[t - off] : 0;
        __syncthreads();
        partials[t] += v;
        __syncthreads();
    }
    int base = partials[t] - sum;     // exclusive base for this chunk
#pragma unroll
    for (int j = 0; j < 16; ++j)
        cursor[t * 16 + j] = base + local[j];
}

__global__ __launch_bounds__(256) void scatter_kernel(
    const float* __restrict__ pos, int n, int* __restrict__ cursor,
    float4* __restrict__ sorted)
{
    int i = blockIdx.x * blockDim.x + threadIdx.x;
    if (i >= n) return;
    float x = pos[3 * i + 0], y = pos[3 * i + 1], z = pos[3 * i + 2];
    int bin = bin_of(x, y, z);
    int slot = atomicAdd(&cursor[bin], 1);
    sorted[slot] = make_float4(x, y, z, __int_as_float(i));
}

__global__ __launch_bounds__(256) void encode_kernel(
    const float4* __restrict__ sorted,  // n records, bin-ordered
    const float4* __restrict__ tab,
    float4* __restrict__ out,           // (N,16) floats = N*4 float4
    int n,
    float s0, float s1, float s2, float s3,
    int r0, int r1, int r2, int r3,
    int o0, int o1, int o2, int o3)
{
    int j = blockIdx.x * blockDim.x + threadIdx.x;
    if (j >= n) return;
    float4 rec = sorted[j];
    int p = __float_as_int(rec.w);
    float4* o = out + (long)p * 4;

    float scales[4] = { s0, s1, s2, s3 };
    int   ress[4]   = { r0, r1, r2, r3 };
    int   offs[4]   = { o0, o1, o2, o3 };

#pragma unroll
    for (int l = 0; l < 4; ++l) {
        float scale = scales[l];
        int   res   = ress[l];
        int   off   = offs[l];

        float hx = rec.x * scale + 0.5f;
        float hy = rec.y * scale + 0.5f;
        float hz = rec.z * scale + 0.5f;
        float gx = floorf(hx), gy = floorf(hy), gz = floorf(hz);
        float wx = hx - gx,   wy = hy - gy,   wz = hz - gz;
        float ox = 1.0f - wx, oy = 1.0f - wy, oz = 1.0f - wz;
        int res2 = res * res;
        int base = off + (int)gx + (int)gy * res + (int)gz * res2;

        float4 acc = make_float4(0.f, 0.f, 0.f, 0.f);
#pragma unroll
        for (int c = 0; c < 8; ++c) {
            int   idx = base + ((c & 1) ? 1 : 0) + ((c & 2) ? res : 0) + ((c & 4) ? res2 : 0);
            float w   = ((c & 1) ? wx : ox) * ((c & 2) ? wy : oy) * ((c & 4) ? wz : oz);
            float4 v  = tab[idx];
            acc.x += w * v.x;
            acc.y += w * v.y;
            acc.z += w * v.z;
            acc.w += w * v.w;
        }
        o[l] = acc;   // 4 stores, same 64B line -> full-line write
    }
}

// Fallback (round-1 kernel) if ws_size is too small for the sort buffers.
__global__ __launch_bounds__(256) void encode_direct_kernel(
    const float* __restrict__ pos, const float4* __restrict__ tab,
    float4* __restrict__ out, int n_points,
    float s0, float s1, float s2, float s3,
    int r0, int r1, int r2, int r3,
    int o0, int o1, int o2, int o3)
{
    int t = blockIdx.x * blockDim.x + threadIdx.x;
    int p = t >> 2;
    if (p >= n_points) return;
    int l = t & 3;
    float scale = (l == 0) ? s0 : (l == 1) ? s1 : (l == 2) ? s2 : s3;
    int   res   = (l == 0) ? r0 : (l == 1) ? r1 : (l == 2) ? r2 : r3;
    int   off   = (l == 0) ? o0 : (l == 1) ? o1 : (l == 2) ? o2 : o3;
    float px = pos[3 * p], py = pos[3 * p + 1], pz = pos[3 * p + 2];
    float hx = px * scale + 0.5f, hy = py * scale + 0.5f, hz = pz * scale + 0.5f;
    float gx = floorf(hx), gy = floorf(hy), gz = floorf(hz);
    float wx = hx - gx, wy = hy - gy, wz = hz - gz;
    float ox = 1.f - wx, oy = 1.f - wy, oz = 1.f - wz;
    int res2 = res * res;
    int base = off + (int)gx + (int)gy * res + (int)gz * res2;
    float4 acc = make_float4(0.f, 0.f, 0.f, 0.f);
#pragma unroll
    for (int c = 0; c < 8; ++c) {
        int   idx = base + ((c & 1) ? 1 : 0) + ((c & 2) ? res : 0) + ((c & 4) ? res2 : 0);
        float w   = ((c & 1) ? wx : ox) * ((c & 2) ? wy : oy) * ((c & 4) ? wz : oz);
        float4 v  = tab[idx];
        acc.x += w * v.x; acc.y += w * v.y; acc.z += w * v.z; acc.w += w * v.w;
    }
    out[t] = acc;
}

extern "C" void kernel_launch(void* const* d_in, const int* in_sizes, int n_in,
                              void* d_out, int out_size, void* d_ws, size_t ws_size,
                              hipStream_t stream) {
    const float*  positions = (const float*)d_in[0];
    const float4* table     = (const float4*)d_in[1];
    float4*       out       = (float4*)d_out;
    int n = in_sizes[0] / 3;

    // Level metadata (double precision, matches Python reference)
    const double B_SCALE = 1.3195079565048218;
    const double BASE = 32.0;
    const long   MAX_PARAMS = 1L << 19;
    float scales[4]; int res[4], offs[4];
    long off = 0;
    for (int l = 0; l < 4; ++l) {
        double s = BASE * pow(B_SCALE, (double)l) - 1.0;
        scales[l] = (float)s;
        int r = (int)ceil(s) + 1;
        res[l] = r;
        offs[l] = (int)off;
        long pcount = (long)r * r * r;
        if (pcount % 8 != 0) pcount = (pcount + 7) / 8 * 8;
        if (pcount > MAX_PARAMS) pcount = MAX_PARAMS;
        off += pcount;
    }

    size_t need = (size_t)NBINS * 4 * 2 + (size_t)n * 16;
    int block = 256;
    int grid_n = (n + block - 1) / block;

    if (ws_size >= need) {
        int*    hist   = (int*)d_ws;                    // NBINS ints
        int*    cursor = hist + NBINS;                  // NBINS ints
        float4* sorted = (float4*)(cursor + NBINS);     // n float4

        hipMemsetAsync(hist, 0, NBINS * sizeof(int), stream);
        hist_kernel<<<grid_n, block, 0, stream>>>(positions, n, hist);
        scan_kernel<<<1, 256, 0, stream>>>(hist, cursor);
        scatter_kernel<<<grid_n, block, 0, stream>>>(positions, n, cursor, sorted);
        encode_kernel<<<grid_n, block, 0, stream>>>(
            sorted, table, out, n,
            scales[0], scales[1], scales[2], scales[3],
            res[0], res[1], res[2], res[3],
            offs[0], offs[1], offs[2], offs[3]);
    } else {
        long n_threads = 4L * n;
        long grid = (n_threads + block - 1) / block;
        encode_direct_kernel<<<dim3((unsigned)grid), dim3(block), 0, stream>>>(
            positions, table, out, n,
            scales[0], scales[1], scales[2], scales[3],
            res[0], res[1], res[2], res[3],
            offs[0], offs[1], offs[2], offs[3]);
    }
}